// Round 11
// baseline (168.467 us; speedup 1.0000x reference)
//
#include <hip/hip_runtime.h>
#include <hip/hip_bf16.h>

#define HIDDEN 768
#define NH 12
#define HD 64
#define BB 4
#define SS 2048
#define M_TOT (BB * SS)      // 8192
#define NQKV (3 * HIDDEN)    // 2304
#define LOG2E 1.44269504f

typedef __attribute__((ext_vector_type(8))) short bf16x8;
typedef __attribute__((ext_vector_type(4))) float f32x4;
typedef __attribute__((ext_vector_type(4))) unsigned int u32x4;

__device__ inline unsigned short f2bf(float x) {
    __hip_bfloat16 h = __float2bfloat16(x);
    return *reinterpret_cast<unsigned short*>(&h);
}

__device__ inline void gl_lds16(const unsigned short* g, unsigned short* s) {
    __builtin_amdgcn_global_load_lds(
        (const __attribute__((address_space(1))) unsigned int*)g,
        (__attribute__((address_space(3))) unsigned int*)s, 16, 0, 0);
}

// ---------------------------------------------------------------------------
// Kernel 1: cast hidden_states and Wq|Wk|Wv to bf16; fused mask prepass.
// ---------------------------------------------------------------------------
__global__ __launch_bounds__(256) void cast_kernel(
    const float* __restrict__ hs, const float* __restrict__ wq,
    const float* __restrict__ wk, const float* __restrict__ wv,
    const int* __restrict__ mask, unsigned short* __restrict__ a_bf,
    unsigned short* __restrict__ w_bf, float* __restrict__ mb,
    int* __restrict__ anym) {
    const int HS_N = M_TOT * HIDDEN / 4;
    const int W_N = HIDDEN * HIDDEN / 4;
    int idx = blockIdx.x * blockDim.x + threadIdx.x;
    if (idx < BB * SS) mb[idx] = mask[idx] ? 0.f : -1e30f;
    if (idx < BB * 32) {
        int b = idx >> 5, t = idx & 31;
        const int* mp = mask + b * SS + t * 64;
        int any = 0;
#pragma unroll 8
        for (int j = 0; j < 64; j++) any |= (mp[j] == 0);
        anym[idx] = any;
    }
    if (idx >= HS_N + 3 * W_N) return;
    if (idx < HS_N) {
        float4 v = ((const float4*)hs)[idx];
        ushort4 o;
        o.x = f2bf(v.x); o.y = f2bf(v.y); o.z = f2bf(v.z); o.w = f2bf(v.w);
        ((ushort4*)a_bf)[idx] = o;
    } else {
        int widx = idx - HS_N;
        const float* src;
        int off;
        if (widx < W_N)        { src = wq; off = widx; }
        else if (widx < 2*W_N) { src = wk; off = widx - W_N; }
        else                   { src = wv; off = widx - 2 * W_N; }
        float4 v = ((const float4*)src)[off];
        ushort4 o;
        o.x = f2bf(v.x); o.y = f2bf(v.y); o.z = f2bf(v.z); o.w = f2bf(v.w);
        ((ushort4*)w_bf)[widx] = o;
    }
}

// ---------------------------------------------------------------------------
// Kernel 2: QKV projection GEMM, m97 structure (verified R6/R8, unchanged).
// ---------------------------------------------------------------------------
__global__ __launch_bounds__(256, 3) void qkv_gemm(
    const unsigned short* __restrict__ A, const unsigned short* __restrict__ W,
    const float* __restrict__ bq, const float* __restrict__ bk,
    const float* __restrict__ bv, unsigned short* __restrict__ qbuf,
    unsigned short* __restrict__ kf, unsigned short* __restrict__ vf) {
    __shared__ unsigned short As[2][128][32];
    __shared__ unsigned short Bs[2][128][32];
    const int tid = threadIdx.x;
    const int m0 = blockIdx.y * 128;
    const int n0 = blockIdx.x * 128;
    const int w = tid >> 6, l = tid & 63;
    const int wm = w >> 1, wn = w & 1;
    const int lrow = l & 15;
    const int g4 = l >> 4;
    const int fcol = (g4 ^ (lrow >> 2)) * 8;

    const int srow = l >> 2;
    const int sslot = (l & 3) ^ ((l >> 4) & 3);
    const unsigned short* pA =
        A + (size_t)(m0 + w * 32 + srow) * HIDDEN + sslot * 8;
    const unsigned short* pB =
        W + (size_t)(n0 + w * 32 + srow) * HIDDEN + sslot * 8;

    f32x4 acc[4][4] = {};

#define STAGE(bb)                                          \
    do {                                                   \
        gl_lds16(pA,               &As[bb][w * 32][0]);    \
        gl_lds16(pA + 16 * HIDDEN, &As[bb][w * 32 + 16][0]); \
        gl_lds16(pB,               &Bs[bb][w * 32][0]);    \
        gl_lds16(pB + 16 * HIDDEN, &Bs[bb][w * 32 + 16][0]); \
        pA += 32; pB += 32;                                \
    } while (0)

    STAGE(0);
    __syncthreads();
    int cur = 0;

    for (int kt = 0; kt < HIDDEN / 32; kt++) {
        if (kt < HIDDEN / 32 - 1) STAGE(cur ^ 1);
        bf16x8 af[4], bfr[4];
#pragma unroll
        for (int mi = 0; mi < 4; mi++)
            af[mi] = *(const bf16x8*)&As[cur][wm * 64 + mi * 16 + lrow][fcol];
#pragma unroll
        for (int ni = 0; ni < 4; ni++)
            bfr[ni] = *(const bf16x8*)&Bs[cur][wn * 64 + ni * 16 + lrow][fcol];
        __builtin_amdgcn_s_setprio(1);
#pragma unroll
        for (int mi = 0; mi < 4; mi++)
#pragma unroll
            for (int ni = 0; ni < 4; ni++)
                acc[mi][ni] = __builtin_amdgcn_mfma_f32_16x16x32_bf16(
                    af[mi], bfr[ni], acc[mi][ni], 0, 0, 0);
        __builtin_amdgcn_s_setprio(0);
        __syncthreads();
        cur ^= 1;
    }
#undef STAGE

    if (n0 < 768) {
#pragma unroll
        for (int mi = 0; mi < 4; mi++)
#pragma unroll
            for (int ni = 0; ni < 4; ni++) {
                int col = n0 + wn * 64 + ni * 16 + lrow;
                float bias = bq[col];
#pragma unroll
                for (int i = 0; i < 4; i++) {
                    int row = m0 + wm * 64 + mi * 16 + g4 * 4 + i;
                    qbuf[(size_t)row * 768 + col] =
                        f2bf((acc[mi][ni][i] + bias) * 0.125f);
                }
            }
    } else if (n0 < 1536) {
#pragma unroll
        for (int mi = 0; mi < 4; mi++)
#pragma unroll
            for (int ni = 0; ni < 4; ni++) {
                int dd = n0 - 768 + wn * 64 + ni * 16 + lrow;
                float bias = bk[dd];
                int hh = dd >> 6, d = dd & 63;
                int gk = d >> 3, d8 = d & 7;
#pragma unroll
                for (int i = 0; i < 4; i++) {
                    int row = m0 + wm * 64 + mi * 16 + g4 * 4 + i;
                    int bb2 = row >> 11, s = row & 2047;
                    int kv16 = s >> 4, ls = s & 15;
                    kf[((size_t)(bb2 * NH + hh) * 128 + kv16) * 1024 +
                       (gk * 16 + ls) * 8 + d8] = f2bf(acc[mi][ni][i] + bias);
                }
            }
    } else {
#pragma unroll
        for (int mi = 0; mi < 4; mi++)
#pragma unroll
            for (int ni = 0; ni < 4; ni++) {
                int dd = n0 - 1536 + wn * 64 + ni * 16 + lrow;
                float bias = bv[dd];
                int hh = dd >> 6, d = dd & 63;
                int dm = d >> 4, lr = d & 15;
                int row0 = m0 + wm * 64 + mi * 16 + g4 * 4;
                int bb2 = row0 >> 11, s = row0 & 2047;
                int kv32 = s >> 5, gv = (s >> 3) & 3, s8 = s & 7;
                ushort4 o;
                o.x = f2bf(acc[mi][ni][0] + bias);
                o.y = f2bf(acc[mi][ni][1] + bias);
                o.z = f2bf(acc[mi][ni][2] + bias);
                o.w = f2bf(acc[mi][ni][3] + bias);
                *(ushort4*)(vf + (((size_t)(bb2 * NH + hh) * 4 + dm) * 64 + kv32) * 512 +
                            (gv * 16 + lr) * 8 + s8) = o;
            }
    }
}

// ---------------------------------------------------------------------------
// Kernel 3: banded flash attention — verified R8 structure with defer-max
// GUARD INTACT. Two safe deltas vs R8:
//  (a) m_run init 14.0 (score upper bound ~8.7 < 22): rescale bodies never
//      execute in practice, but the guard still protects correctness.
//  (b) XCD-bijective block swizzle (1536 = 8*192): same-(b,h) blocks share
//      an XCD's L2 for K/V band locality. Pure index remap.
// ---------------------------------------------------------------------------
__global__ __launch_bounds__(256) void attn_kernel(
    const unsigned short* __restrict__ Qb, const unsigned short* __restrict__ KF,
    const unsigned short* __restrict__ VF, const float* __restrict__ MB,
    const int* __restrict__ ANYM, float* __restrict__ out) {
    __shared__ unsigned short Kl[2][4096];
    __shared__ unsigned short Vl[2][4096];

    const int head_order[12] = {6, 7, 5, 4, 3, 11, 2, 10, 1, 9, 0, 8};
    const int Rtab[12]       = {31, 31, 19, 10, 5, 4, 3, 2, 2, 1, 1, 1};

    const int tid = threadIdx.x;
    const int w = tid >> 6, l = tid & 63;
    // XCD-bijective swizzle: flat in [0,1536), 1536 % 8 == 0
    const int flat = blockIdx.y * gridDim.x + blockIdx.x;
    const int swz = (flat & 7) * 192 + (flat >> 3);
    const int qt = swz & 31;
    const int byy = swz >> 5;         // 0..47
    const int hidx = byy >> 2;
    const int b = byy & 3;
    const int h = head_order[hidx];
    const int R = Rtab[hidx];
    const int bh = b * NH + h;
    const int lrow = l & 15;
    const int g = l >> 4;
    const int q = qt * 64 + w * 16 + lrow;
    const int l8 = l * 8;

    const float slope = (h < 8) ? exp2f(-(float)(h + 1))
                                : exp2f(-((float)(h - 8) + 0.5f));
    const float nslope2 = -slope * LOG2E;
    const float stp = 64.f * nslope2;

    const unsigned short* qp = Qb + (size_t)(b * SS + q) * 768 + h * HD + g * 8;
    const bf16x8 qf0 = *(const bf16x8*)(qp);
    const bf16x8 qf1 = *(const bf16x8*)(qp + 32);

    const unsigned short* kfb = KF + (size_t)bh * 128 * 1024;
    const unsigned short* vfb = VF + (size_t)bh * 4 * 64 * 512;
    const float* mbp = MB + b * SS + g * 4;
    const int* anyp = ANYM + b * 32;

    bf16x8 ones;
#pragma unroll
    for (int j = 0; j < 8; j++) ones[j] = (short)0x3F80;

    f32x4 accT[4] = {};
    f32x4 lacc = {};
    float m_run = 14.0f;   // upper bound on row-max sv; guard below stays live
    float ta[16];
    bool need_full = true;

    const int kt_lo = max(0, qt - R);
    const int kt_hi = min(31, qt + R);

    {
        const unsigned short* gk0 = kfb + ((size_t)kt_lo * 4 + w) * 1024 + l8;
        const unsigned short* gv0 = vfb + ((size_t)w * 64 + kt_lo * 2) * 512 + l8;
        gl_lds16(gk0,       &Kl[0][w * 1024]);
        gl_lds16(gk0 + 512, &Kl[0][w * 1024 + 512]);
        gl_lds16(gv0,       &Vl[0][w * 1024]);
        gl_lds16(gv0 + 512, &Vl[0][w * 1024 + 512]);
    }
    __syncthreads();

    const unsigned short* gk = kfb + ((size_t)(kt_lo + 1) * 4 + w) * 1024 + l8;
    const unsigned short* gv = vfb + ((size_t)w * 64 + (size_t)(kt_lo + 1) * 2) * 512 + l8;
    int cur = 0;

    for (int kt = kt_lo; kt <= kt_hi; kt++) {
        if (kt < kt_hi) {
            gl_lds16(gk,       &Kl[cur ^ 1][w * 1024]);
            gl_lds16(gk + 512, &Kl[cur ^ 1][w * 1024 + 512]);
            gl_lds16(gv,       &Vl[cur ^ 1][w * 1024]);
            gl_lds16(gv + 512, &Vl[cur ^ 1][w * 1024 + 512]);
            gk += 4096;
            gv += 1024;
        }

        f32x4 s4[4];
        __builtin_amdgcn_s_setprio(1);
#pragma unroll
        for (int nf = 0; nf < 4; nf++) {
            bf16x8 k0 = *(const bf16x8*)&Kl[cur][nf * 1024 + l8];
            bf16x8 k1 = *(const bf16x8*)&Kl[cur][nf * 1024 + 512 + l8];
            f32x4 z = {};
            z = __builtin_amdgcn_mfma_f32_16x16x32_bf16(k0, qf0, z, 0, 0, 0);
            z = __builtin_amdgcn_mfma_f32_16x16x32_bf16(k1, qf1, z, 0, 0, 0);
            s4[nf] = z;
        }
        __builtin_amdgcn_s_setprio(0);

        if (need_full || kt == qt || kt == qt + 1) {
            const float fdf = (float)(kt * 64 + g * 4 - q);
#pragma unroll
            for (int nf = 0; nf < 4; nf++)
#pragma unroll
                for (int i = 0; i < 4; i++)
                    ta[nf * 4 + i] = fabsf(fdf + (float)(nf * 16 + i)) * nslope2;
        } else {
            const float d = (kt > qt) ? stp : -stp;
#pragma unroll
            for (int e = 0; e < 16; e++) ta[e] += d;
        }
        need_full = false;

        float sv[16];
#pragma unroll
        for (int nf = 0; nf < 4; nf++)
#pragma unroll
            for (int i = 0; i < 4; i++)
                sv[nf * 4 + i] = fmaf(s4[nf][i], LOG2E, ta[nf * 4 + i]);
        if (anyp[kt]) {
#pragma unroll
            for (int nf = 0; nf < 4; nf++) {
                float4 mbv = *(const float4*)(mbp + kt * 64 + nf * 16);
                sv[nf * 4 + 0] += mbv.x;
                sv[nf * 4 + 1] += mbv.y;
                sv[nf * 4 + 2] += mbv.z;
                sv[nf * 4 + 3] += mbv.w;
            }
        }

        float t0 = fmaxf(fmaxf(sv[0], sv[1]), sv[2]);
        float t1 = fmaxf(fmaxf(sv[3], sv[4]), sv[5]);
        float t2 = fmaxf(fmaxf(sv[6], sv[7]), sv[8]);
        float t3 = fmaxf(fmaxf(sv[9], sv[10]), sv[11]);
        float t4 = fmaxf(fmaxf(sv[12], sv[13]), sv[14]);
        float mt = fmaxf(fmaxf(fmaxf(t0, t1), fmaxf(t2, t3)), fmaxf(t4, sv[15]));
        mt = fmaxf(mt, __shfl_xor(mt, 16));
        mt = fmaxf(mt, __shfl_xor(mt, 32));

        if (!__all(mt <= m_run + 8.0f)) {
            float mnew = fmaxf(m_run, mt);
            float corr = __builtin_amdgcn_exp2f(m_run - mnew);
            m_run = mnew;
#pragma unroll
            for (int i = 0; i < 4; i++) lacc[i] *= corr;
#pragma unroll
            for (int m = 0; m < 4; m++)
#pragma unroll
                for (int i = 0; i < 4; i++) accT[m][i] *= corr;
        }

        float p[16];
#pragma unroll
        for (int e = 0; e < 16; e++)
            p[e] = __builtin_amdgcn_exp2f(sv[e] - m_run);

        unsigned pk[4][2];
#pragma unroll
        for (int nf = 0; nf < 4; nf++) {
            asm("v_cvt_pk_bf16_f32 %0, %1, %2"
                : "=v"(pk[nf][0]) : "v"(p[nf * 4 + 0]), "v"(p[nf * 4 + 1]));
            asm("v_cvt_pk_bf16_f32 %0, %1, %2"
                : "=v"(pk[nf][1]) : "v"(p[nf * 4 + 2]), "v"(p[nf * 4 + 3]));
        }

        const int dstA = ((((g & 1) << 1) | (g >> 1)) << 4) | lrow;
        const int idxA = dstA << 2;
        const int idxB = idxA ^ 128;
        const bool odd = (g & 1);
        unsigned rA0 = __builtin_amdgcn_ds_permute(idxA, (int)(odd ? pk[1][0] : pk[0][0]));
        unsigned rA1 = __builtin_amdgcn_ds_permute(idxA, (int)(odd ? pk[1][1] : pk[0][1]));
        unsigned rB0 = __builtin_amdgcn_ds_permute(idxB, (int)(odd ? pk[0][0] : pk[1][0]));
        unsigned rB1 = __builtin_amdgcn_ds_permute(idxB, (int)(odd ? pk[0][1] : pk[1][1]));
        unsigned rA2 = __builtin_amdgcn_ds_permute(idxA, (int)(odd ? pk[3][0] : pk[2][0]));
        unsigned rA3 = __builtin_amdgcn_ds_permute(idxA, (int)(odd ? pk[3][1] : pk[2][1]));
        unsigned rB2 = __builtin_amdgcn_ds_permute(idxB, (int)(odd ? pk[2][0] : pk[3][0]));
        unsigned rB3 = __builtin_amdgcn_ds_permute(idxB, (int)(odd ? pk[2][1] : pk[3][1]));
        const bool hi = (g >> 1);
        u32x4 uf0, uf1;
        uf0.x = hi ? rB0 : rA0; uf0.y = hi ? rB1 : rA1;
        uf0.z = hi ? rA0 : rB0; uf0.w = hi ? rA1 : rB1;
        uf1.x = hi ? rB2 : rA2; uf1.y = hi ? rB3 : rA3;
        uf1.z = hi ? rA2 : rB2; uf1.w = hi ? rA3 : rB3;
        bf16x8 pf0 = __builtin_bit_cast(bf16x8, uf0);
        bf16x8 pf1 = __builtin_bit_cast(bf16x8, uf1);

        __builtin_amdgcn_s_setprio(1);
#pragma unroll
        for (int m = 0; m < 4; m++) {
            bf16x8 v0 = *(const bf16x8*)&Vl[cur][m * 1024 + l8];
            bf16x8 v1 = *(const bf16x8*)&Vl[cur][m * 1024 + 512 + l8];
            accT[m] = __builtin_amdgcn_mfma_f32_16x16x32_bf16(v0, pf0, accT[m], 0, 0, 0);
            accT[m] = __builtin_amdgcn_mfma_f32_16x16x32_bf16(v1, pf1, accT[m], 0, 0, 0);
        }
        lacc = __builtin_amdgcn_mfma_f32_16x16x32_bf16(ones, pf0, lacc, 0, 0, 0);
        lacc = __builtin_amdgcn_mfma_f32_16x16x32_bf16(ones, pf1, lacc, 0, 0, 0);
        __builtin_amdgcn_s_setprio(0);

        __syncthreads();
        cur ^= 1;
    }

    const float inv = 1.0f / lacc[0];
    float* op = out + (size_t)(b * SS + q) * HIDDEN + h * HD + g * 4;
#pragma unroll
    for (int m = 0; m < 4; m++) {
        float4 o;
        o.x = accT[m][0] * inv; o.y = accT[m][1] * inv;
        o.z = accT[m][2] * inv; o.w = accT[m][3] * inv;
        *(float4*)(op + m * 16) = o;
    }
}

// ---------------------------------------------------------------------------
extern "C" void kernel_launch(void* const* d_in, const int* in_sizes, int n_in,
                              void* d_out, int out_size, void* d_ws,
                              size_t ws_size, hipStream_t stream) {
    const float* hs = (const float*)d_in[0];
    const float* wq = (const float*)d_in[1];
    const float* bq = (const float*)d_in[2];
    const float* wk = (const float*)d_in[3];
    const float* bk = (const float*)d_in[4];
    const float* wv = (const float*)d_in[5];
    const float* bv = (const float*)d_in[6];
    const int* mask = (const int*)d_in[7];
    float* out = (float*)d_out;

    unsigned short* a_bf = (unsigned short*)d_ws;
    unsigned short* w_bf = a_bf + (size_t)M_TOT * HIDDEN;
    unsigned short* qbuf = w_bf + (size_t)NQKV * HIDDEN;
    unsigned short* kf = qbuf + (size_t)M_TOT * 768;
    unsigned short* vf = kf + (size_t)BB * NH * 128 * 1024;
    float* mb = (float*)(vf + (size_t)BB * NH * 4 * 64 * 512);
    int* anym = (int*)(mb + BB * SS);

    int castN = (M_TOT * HIDDEN + 3 * HIDDEN * HIDDEN) / 4;
    cast_kernel<<<(castN + 255) / 256, 256, 0, stream>>>(
        hs, wq, wk, wv, mask, a_bf, w_bf, mb, anym);

    dim3 ggrid(NQKV / 128, M_TOT / 128);  // (18, 64)
    qkv_gemm<<<ggrid, 256, 0, stream>>>(a_bf, w_bf, bq, bk, bv, qbuf, kf, vf);

    dim3 agrid(SS / 64, NH * BB);  // (32, 48)
    attn_kernel<<<agrid, 256, 0, stream>>>(qbuf, kf, vf, mb, anym, out);
}

// Round 12
// 112.797 us; speedup vs baseline: 1.4935x; 1.4935x over previous
//
#include <hip/hip_runtime.h>
#include <hip/hip_bf16.h>

#define HIDDEN 768
#define NH 12
#define HD 64
#define BB 4
#define SS 2048
#define M_TOT (BB * SS)      // 8192
#define NQKV (3 * HIDDEN)    // 2304
#define LOG2E 1.44269504f

typedef __attribute__((ext_vector_type(8))) short bf16x8;
typedef __attribute__((ext_vector_type(4))) float f32x4;
typedef __attribute__((ext_vector_type(4))) unsigned int u32x4;

__device__ inline unsigned short f2bf(float x) {
    __hip_bfloat16 h = __float2bfloat16(x);
    return *reinterpret_cast<unsigned short*>(&h);
}

__device__ inline void gl_lds16(const unsigned short* g, unsigned short* s) {
    __builtin_amdgcn_global_load_lds(
        (const __attribute__((address_space(1))) unsigned int*)g,
        (__attribute__((address_space(3))) unsigned int*)s, 16, 0, 0);
}

// ---------------------------------------------------------------------------
// Kernel 1: cast hidden_states and Wq|Wk|Wv to bf16; fused mask prepass.
// ---------------------------------------------------------------------------
__global__ __launch_bounds__(256) void cast_kernel(
    const float* __restrict__ hs, const float* __restrict__ wq,
    const float* __restrict__ wk, const float* __restrict__ wv,
    const int* __restrict__ mask, unsigned short* __restrict__ a_bf,
    unsigned short* __restrict__ w_bf, float* __restrict__ mb,
    int* __restrict__ anym) {
    const int HS_N = M_TOT * HIDDEN / 4;
    const int W_N = HIDDEN * HIDDEN / 4;
    int idx = blockIdx.x * blockDim.x + threadIdx.x;
    if (idx < BB * SS) mb[idx] = mask[idx] ? 0.f : -1e30f;
    if (idx < BB * 32) {
        int b = idx >> 5, t = idx & 31;
        const int* mp = mask + b * SS + t * 64;
        int any = 0;
#pragma unroll 8
        for (int j = 0; j < 64; j++) any |= (mp[j] == 0);
        anym[idx] = any;
    }
    if (idx >= HS_N + 3 * W_N) return;
    if (idx < HS_N) {
        float4 v = ((const float4*)hs)[idx];
        ushort4 o;
        o.x = f2bf(v.x); o.y = f2bf(v.y); o.z = f2bf(v.z); o.w = f2bf(v.w);
        ((ushort4*)a_bf)[idx] = o;
    } else {
        int widx = idx - HS_N;
        const float* src;
        int off;
        if (widx < W_N)        { src = wq; off = widx; }
        else if (widx < 2*W_N) { src = wk; off = widx - W_N; }
        else                   { src = wv; off = widx - 2 * W_N; }
        float4 v = ((const float4*)src)[off];
        ushort4 o;
        o.x = f2bf(v.x); o.y = f2bf(v.y); o.z = f2bf(v.z); o.w = f2bf(v.w);
        ((ushort4*)w_bf)[widx] = o;
    }
}

// ---------------------------------------------------------------------------
// Kernel 2: QKV projection GEMM, m97 structure (verified R6/R8, unchanged).
// ---------------------------------------------------------------------------
__global__ __launch_bounds__(256, 3) void qkv_gemm(
    const unsigned short* __restrict__ A, const unsigned short* __restrict__ W,
    const float* __restrict__ bq, const float* __restrict__ bk,
    const float* __restrict__ bv, unsigned short* __restrict__ qbuf,
    unsigned short* __restrict__ kf, unsigned short* __restrict__ vf) {
    __shared__ unsigned short As[2][128][32];
    __shared__ unsigned short Bs[2][128][32];
    const int tid = threadIdx.x;
    const int m0 = blockIdx.y * 128;
    const int n0 = blockIdx.x * 128;
    const int w = tid >> 6, l = tid & 63;
    const int wm = w >> 1, wn = w & 1;
    const int lrow = l & 15;
    const int g4 = l >> 4;
    const int fcol = (g4 ^ (lrow >> 2)) * 8;

    const int srow = l >> 2;
    const int sslot = (l & 3) ^ ((l >> 4) & 3);
    const unsigned short* pA =
        A + (size_t)(m0 + w * 32 + srow) * HIDDEN + sslot * 8;
    const unsigned short* pB =
        W + (size_t)(n0 + w * 32 + srow) * HIDDEN + sslot * 8;

    f32x4 acc[4][4] = {};

#define STAGE(bb)                                          \
    do {                                                   \
        gl_lds16(pA,               &As[bb][w * 32][0]);    \
        gl_lds16(pA + 16 * HIDDEN, &As[bb][w * 32 + 16][0]); \
        gl_lds16(pB,               &Bs[bb][w * 32][0]);    \
        gl_lds16(pB + 16 * HIDDEN, &Bs[bb][w * 32 + 16][0]); \
        pA += 32; pB += 32;                                \
    } while (0)

    STAGE(0);
    __syncthreads();
    int cur = 0;

    for (int kt = 0; kt < HIDDEN / 32; kt++) {
        if (kt < HIDDEN / 32 - 1) STAGE(cur ^ 1);
        bf16x8 af[4], bfr[4];
#pragma unroll
        for (int mi = 0; mi < 4; mi++)
            af[mi] = *(const bf16x8*)&As[cur][wm * 64 + mi * 16 + lrow][fcol];
#pragma unroll
        for (int ni = 0; ni < 4; ni++)
            bfr[ni] = *(const bf16x8*)&Bs[cur][wn * 64 + ni * 16 + lrow][fcol];
        __builtin_amdgcn_s_setprio(1);
#pragma unroll
        for (int mi = 0; mi < 4; mi++)
#pragma unroll
            for (int ni = 0; ni < 4; ni++)
                acc[mi][ni] = __builtin_amdgcn_mfma_f32_16x16x32_bf16(
                    af[mi], bfr[ni], acc[mi][ni], 0, 0, 0);
        __builtin_amdgcn_s_setprio(0);
        __syncthreads();
        cur ^= 1;
    }
#undef STAGE

    if (n0 < 768) {
#pragma unroll
        for (int mi = 0; mi < 4; mi++)
#pragma unroll
            for (int ni = 0; ni < 4; ni++) {
                int col = n0 + wn * 64 + ni * 16 + lrow;
                float bias = bq[col];
#pragma unroll
                for (int i = 0; i < 4; i++) {
                    int row = m0 + wm * 64 + mi * 16 + g4 * 4 + i;
                    qbuf[(size_t)row * 768 + col] =
                        f2bf((acc[mi][ni][i] + bias) * 0.125f);
                }
            }
    } else if (n0 < 1536) {
#pragma unroll
        for (int mi = 0; mi < 4; mi++)
#pragma unroll
            for (int ni = 0; ni < 4; ni++) {
                int dd = n0 - 768 + wn * 64 + ni * 16 + lrow;
                float bias = bk[dd];
                int hh = dd >> 6, d = dd & 63;
                int gk = d >> 3, d8 = d & 7;
#pragma unroll
                for (int i = 0; i < 4; i++) {
                    int row = m0 + wm * 64 + mi * 16 + g4 * 4 + i;
                    int bb2 = row >> 11, s = row & 2047;
                    int kv16 = s >> 4, ls = s & 15;
                    kf[((size_t)(bb2 * NH + hh) * 128 + kv16) * 1024 +
                       (gk * 16 + ls) * 8 + d8] = f2bf(acc[mi][ni][i] + bias);
                }
            }
    } else {
#pragma unroll
        for (int mi = 0; mi < 4; mi++)
#pragma unroll
            for (int ni = 0; ni < 4; ni++) {
                int dd = n0 - 1536 + wn * 64 + ni * 16 + lrow;
                float bias = bv[dd];
                int hh = dd >> 6, d = dd & 63;
                int dm = d >> 4, lr = d & 15;
                int row0 = m0 + wm * 64 + mi * 16 + g4 * 4;
                int bb2 = row0 >> 11, s = row0 & 2047;
                int kv32 = s >> 5, gv = (s >> 3) & 3, s8 = s & 7;
                ushort4 o;
                o.x = f2bf(acc[mi][ni][0] + bias);
                o.y = f2bf(acc[mi][ni][1] + bias);
                o.z = f2bf(acc[mi][ni][2] + bias);
                o.w = f2bf(acc[mi][ni][3] + bias);
                *(ushort4*)(vf + (((size_t)(bb2 * NH + hh) * 4 + dm) * 64 + kv32) * 512 +
                            (gv * 16 + lr) * 8 + s8) = o;
            }
    }
}

// ---------------------------------------------------------------------------
// Kernel 3: banded flash attention (verified R8 inner loop). New block
// remap keeps BOTH R11's L2 locality AND R8's heavy-first dispatch:
//   xcd = flat%8 (constant per byy -> same-(b,h) blocks share one XCD L2)
//   slot-major order: flat 0..255 = byy 0..7 = the eight R=31 groups first;
//   the late tail is only R<=2 blocks. m_run init 14.0 (guard intact).
// ---------------------------------------------------------------------------
__global__ __launch_bounds__(256) void attn_kernel(
    const unsigned short* __restrict__ Qb, const unsigned short* __restrict__ KF,
    const unsigned short* __restrict__ VF, const float* __restrict__ MB,
    const int* __restrict__ ANYM, float* __restrict__ out) {
    __shared__ unsigned short Kl[2][4096];
    __shared__ unsigned short Vl[2][4096];

    const int head_order[12] = {6, 7, 5, 4, 3, 11, 2, 10, 1, 9, 0, 8};
    const int Rtab[12]       = {31, 31, 19, 10, 5, 4, 3, 2, 2, 1, 1, 1};

    const int tid = threadIdx.x;
    const int w = tid >> 6, l = tid & 63;
    // bijective remap of hw dispatch index (1536 blocks):
    // flat = (slot*32 + qt)*8 + xcd ; byy = slot*8 + xcd
    const int flat = blockIdx.y * gridDim.x + blockIdx.x;
    const int xcd = flat & 7;
    const int rem = flat >> 3;        // 0..191
    const int slot = rem >> 5;        // 0..5
    const int qt = rem & 31;
    const int byy = slot * 8 + xcd;   // 0..47
    const int hidx = byy >> 2;
    const int b = byy & 3;
    const int h = head_order[hidx];
    const int R = Rtab[hidx];
    const int bh = b * NH + h;
    const int lrow = l & 15;
    const int g = l >> 4;
    const int q = qt * 64 + w * 16 + lrow;
    const int l8 = l * 8;

    const float slope = (h < 8) ? exp2f(-(float)(h + 1))
                                : exp2f(-((float)(h - 8) + 0.5f));
    const float nslope2 = -slope * LOG2E;
    const float stp = 64.f * nslope2;

    const unsigned short* qp = Qb + (size_t)(b * SS + q) * 768 + h * HD + g * 8;
    const bf16x8 qf0 = *(const bf16x8*)(qp);
    const bf16x8 qf1 = *(const bf16x8*)(qp + 32);

    const unsigned short* kfb = KF + (size_t)bh * 128 * 1024;
    const unsigned short* vfb = VF + (size_t)bh * 4 * 64 * 512;
    const float* mbp = MB + b * SS + g * 4;
    const int* anyp = ANYM + b * 32;

    bf16x8 ones;
#pragma unroll
    for (int j = 0; j < 8; j++) ones[j] = (short)0x3F80;

    f32x4 accT[4] = {};
    f32x4 lacc = {};
    float m_run = 14.0f;   // upper bound on row-max sv; guard below stays live
    float ta[16];
    bool need_full = true;

    const int kt_lo = max(0, qt - R);
    const int kt_hi = min(31, qt + R);

    {
        const unsigned short* gk0 = kfb + ((size_t)kt_lo * 4 + w) * 1024 + l8;
        const unsigned short* gv0 = vfb + ((size_t)w * 64 + kt_lo * 2) * 512 + l8;
        gl_lds16(gk0,       &Kl[0][w * 1024]);
        gl_lds16(gk0 + 512, &Kl[0][w * 1024 + 512]);
        gl_lds16(gv0,       &Vl[0][w * 1024]);
        gl_lds16(gv0 + 512, &Vl[0][w * 1024 + 512]);
    }
    __syncthreads();

    const unsigned short* gk = kfb + ((size_t)(kt_lo + 1) * 4 + w) * 1024 + l8;
    const unsigned short* gv = vfb + ((size_t)w * 64 + (size_t)(kt_lo + 1) * 2) * 512 + l8;
    int cur = 0;

    for (int kt = kt_lo; kt <= kt_hi; kt++) {
        if (kt < kt_hi) {
            gl_lds16(gk,       &Kl[cur ^ 1][w * 1024]);
            gl_lds16(gk + 512, &Kl[cur ^ 1][w * 1024 + 512]);
            gl_lds16(gv,       &Vl[cur ^ 1][w * 1024]);
            gl_lds16(gv + 512, &Vl[cur ^ 1][w * 1024 + 512]);
            gk += 4096;
            gv += 1024;
        }

        f32x4 s4[4];
        __builtin_amdgcn_s_setprio(1);
#pragma unroll
        for (int nf = 0; nf < 4; nf++) {
            bf16x8 k0 = *(const bf16x8*)&Kl[cur][nf * 1024 + l8];
            bf16x8 k1 = *(const bf16x8*)&Kl[cur][nf * 1024 + 512 + l8];
            f32x4 z = {};
            z = __builtin_amdgcn_mfma_f32_16x16x32_bf16(k0, qf0, z, 0, 0, 0);
            z = __builtin_amdgcn_mfma_f32_16x16x32_bf16(k1, qf1, z, 0, 0, 0);
            s4[nf] = z;
        }
        __builtin_amdgcn_s_setprio(0);

        if (need_full || kt == qt || kt == qt + 1) {
            const float fdf = (float)(kt * 64 + g * 4 - q);
#pragma unroll
            for (int nf = 0; nf < 4; nf++)
#pragma unroll
                for (int i = 0; i < 4; i++)
                    ta[nf * 4 + i] = fabsf(fdf + (float)(nf * 16 + i)) * nslope2;
        } else {
            const float d = (kt > qt) ? stp : -stp;
#pragma unroll
            for (int e = 0; e < 16; e++) ta[e] += d;
        }
        need_full = false;

        float sv[16];
#pragma unroll
        for (int nf = 0; nf < 4; nf++)
#pragma unroll
            for (int i = 0; i < 4; i++)
                sv[nf * 4 + i] = fmaf(s4[nf][i], LOG2E, ta[nf * 4 + i]);
        if (anyp[kt]) {
#pragma unroll
            for (int nf = 0; nf < 4; nf++) {
                float4 mbv = *(const float4*)(mbp + kt * 64 + nf * 16);
                sv[nf * 4 + 0] += mbv.x;
                sv[nf * 4 + 1] += mbv.y;
                sv[nf * 4 + 2] += mbv.z;
                sv[nf * 4 + 3] += mbv.w;
            }
        }

        float t0 = fmaxf(fmaxf(sv[0], sv[1]), sv[2]);
        float t1 = fmaxf(fmaxf(sv[3], sv[4]), sv[5]);
        float t2 = fmaxf(fmaxf(sv[6], sv[7]), sv[8]);
        float t3 = fmaxf(fmaxf(sv[9], sv[10]), sv[11]);
        float t4 = fmaxf(fmaxf(sv[12], sv[13]), sv[14]);
        float mt = fmaxf(fmaxf(fmaxf(t0, t1), fmaxf(t2, t3)), fmaxf(t4, sv[15]));
        mt = fmaxf(mt, __shfl_xor(mt, 16));
        mt = fmaxf(mt, __shfl_xor(mt, 32));

        if (!__all(mt <= m_run + 8.0f)) {
            float mnew = fmaxf(m_run, mt);
            float corr = __builtin_amdgcn_exp2f(m_run - mnew);
            m_run = mnew;
#pragma unroll
            for (int i = 0; i < 4; i++) lacc[i] *= corr;
#pragma unroll
            for (int m = 0; m < 4; m++)
#pragma unroll
                for (int i = 0; i < 4; i++) accT[m][i] *= corr;
        }

        float p[16];
#pragma unroll
        for (int e = 0; e < 16; e++)
            p[e] = __builtin_amdgcn_exp2f(sv[e] - m_run);

        unsigned pk[4][2];
#pragma unroll
        for (int nf = 0; nf < 4; nf++) {
            asm("v_cvt_pk_bf16_f32 %0, %1, %2"
                : "=v"(pk[nf][0]) : "v"(p[nf * 4 + 0]), "v"(p[nf * 4 + 1]));
            asm("v_cvt_pk_bf16_f32 %0, %1, %2"
                : "=v"(pk[nf][1]) : "v"(p[nf * 4 + 2]), "v"(p[nf * 4 + 3]));
        }

        const int dstA = ((((g & 1) << 1) | (g >> 1)) << 4) | lrow;
        const int idxA = dstA << 2;
        const int idxB = idxA ^ 128;
        const bool odd = (g & 1);
        unsigned rA0 = __builtin_amdgcn_ds_permute(idxA, (int)(odd ? pk[1][0] : pk[0][0]));
        unsigned rA1 = __builtin_amdgcn_ds_permute(idxA, (int)(odd ? pk[1][1] : pk[0][1]));
        unsigned rB0 = __builtin_amdgcn_ds_permute(idxB, (int)(odd ? pk[0][0] : pk[1][0]));
        unsigned rB1 = __builtin_amdgcn_ds_permute(idxB, (int)(odd ? pk[0][1] : pk[1][1]));
        unsigned rA2 = __builtin_amdgcn_ds_permute(idxA, (int)(odd ? pk[3][0] : pk[2][0]));
        unsigned rA3 = __builtin_amdgcn_ds_permute(idxA, (int)(odd ? pk[3][1] : pk[2][1]));
        unsigned rB2 = __builtin_amdgcn_ds_permute(idxB, (int)(odd ? pk[2][0] : pk[3][0]));
        unsigned rB3 = __builtin_amdgcn_ds_permute(idxB, (int)(odd ? pk[2][1] : pk[3][1]));
        const bool hi = (g >> 1);
        u32x4 uf0, uf1;
        uf0.x = hi ? rB0 : rA0; uf0.y = hi ? rB1 : rA1;
        uf0.z = hi ? rA0 : rB0; uf0.w = hi ? rA1 : rB1;
        uf1.x = hi ? rB2 : rA2; uf1.y = hi ? rB3 : rA3;
        uf1.z = hi ? rA2 : rB2; uf1.w = hi ? rA3 : rB3;
        bf16x8 pf0 = __builtin_bit_cast(bf16x8, uf0);
        bf16x8 pf1 = __builtin_bit_cast(bf16x8, uf1);

        __builtin_amdgcn_s_setprio(1);
#pragma unroll
        for (int m = 0; m < 4; m++) {
            bf16x8 v0 = *(const bf16x8*)&Vl[cur][m * 1024 + l8];
            bf16x8 v1 = *(const bf16x8*)&Vl[cur][m * 1024 + 512 + l8];
            accT[m] = __builtin_amdgcn_mfma_f32_16x16x32_bf16(v0, pf0, accT[m], 0, 0, 0);
            accT[m] = __builtin_amdgcn_mfma_f32_16x16x32_bf16(v1, pf1, accT[m], 0, 0, 0);
        }
        lacc = __builtin_amdgcn_mfma_f32_16x16x32_bf16(ones, pf0, lacc, 0, 0, 0);
        lacc = __builtin_amdgcn_mfma_f32_16x16x32_bf16(ones, pf1, lacc, 0, 0, 0);
        __builtin_amdgcn_s_setprio(0);

        __syncthreads();
        cur ^= 1;
    }

    const float inv = 1.0f / lacc[0];
    float* op = out + (size_t)(b * SS + q) * HIDDEN + h * HD + g * 4;
#pragma unroll
    for (int m = 0; m < 4; m++) {
        float4 o;
        o.x = accT[m][0] * inv; o.y = accT[m][1] * inv;
        o.z = accT[m][2] * inv; o.w = accT[m][3] * inv;
        *(float4*)(op + m * 16) = o;
    }
}

// ---------------------------------------------------------------------------
extern "C" void kernel_launch(void* const* d_in, const int* in_sizes, int n_in,
                              void* d_out, int out_size, void* d_ws,
                              size_t ws_size, hipStream_t stream) {
    const float* hs = (const float*)d_in[0];
    const float* wq = (const float*)d_in[1];
    const float* bq = (const float*)d_in[2];
    const float* wk = (const float*)d_in[3];
    const float* bk = (const float*)d_in[4];
    const float* wv = (const float*)d_in[5];
    const float* bv = (const float*)d_in[6];
    const int* mask = (const int*)d_in[7];
    float* out = (float*)d_out;

    unsigned short* a_bf = (unsigned short*)d_ws;
    unsigned short* w_bf = a_bf + (size_t)M_TOT * HIDDEN;
    unsigned short* qbuf = w_bf + (size_t)NQKV * HIDDEN;
    unsigned short* kf = qbuf + (size_t)M_TOT * 768;
    unsigned short* vf = kf + (size_t)BB * NH * 128 * 1024;
    float* mb = (float*)(vf + (size_t)BB * NH * 4 * 64 * 512);
    int* anym = (int*)(mb + BB * SS);

    int castN = (M_TOT * HIDDEN + 3 * HIDDEN * HIDDEN) / 4;
    cast_kernel<<<(castN + 255) / 256, 256, 0, stream>>>(
        hs, wq, wk, wv, mask, a_bf, w_bf, mb, anym);

    dim3 ggrid(NQKV / 128, M_TOT / 128);  // (18, 64)
    qkv_gemm<<<ggrid, 256, 0, stream>>>(a_bf, w_bf, bq, bk, bv, qbuf, kf, vf);

    dim3 agrid(SS / 64, NH * BB);  // (32, 48)
    attn_kernel<<<agrid, 256, 0, stream>>>(qbuf, kf, vf, mb, anym, out);
}

// Round 13
// 112.482 us; speedup vs baseline: 1.4977x; 1.0028x over previous
//
#include <hip/hip_runtime.h>
#include <hip/hip_bf16.h>

#define HIDDEN 768
#define NH 12
#define HD 64
#define BB 4
#define SS 2048
#define M_TOT (BB * SS)      // 8192
#define NQKV (3 * HIDDEN)    // 2304
#define LOG2E 1.44269504f

typedef __attribute__((ext_vector_type(8))) short bf16x8;
typedef __attribute__((ext_vector_type(4))) float f32x4;
typedef __attribute__((ext_vector_type(4))) unsigned int u32x4;

__device__ inline unsigned short f2bf(float x) {
    __hip_bfloat16 h = __float2bfloat16(x);
    return *reinterpret_cast<unsigned short*>(&h);
}

__device__ inline void gl_lds16(const unsigned short* g, unsigned short* s) {
    __builtin_amdgcn_global_load_lds(
        (const __attribute__((address_space(1))) unsigned int*)g,
        (__attribute__((address_space(3))) unsigned int*)s, 16, 0, 0);
}

// counted-vmcnt barrier (T4): keep the newest stage-call (4 DMAs/wave) in
// flight across the barrier; drain only the previous iteration's DMAs.
__device__ inline void bar_vm4() {
    __builtin_amdgcn_sched_barrier(0);
    asm volatile("s_waitcnt vmcnt(4)" ::: "memory");
    __builtin_amdgcn_s_barrier();
    __builtin_amdgcn_sched_barrier(0);
}
__device__ inline void bar_vm0() {
    __builtin_amdgcn_sched_barrier(0);
    asm volatile("s_waitcnt vmcnt(0)" ::: "memory");
    __builtin_amdgcn_s_barrier();
    __builtin_amdgcn_sched_barrier(0);
}

// ---------------------------------------------------------------------------
// Kernel 1: cast hidden_states and Wq|Wk|Wv to bf16; fused mask prepass.
// ---------------------------------------------------------------------------
__global__ __launch_bounds__(256) void cast_kernel(
    const float* __restrict__ hs, const float* __restrict__ wq,
    const float* __restrict__ wk, const float* __restrict__ wv,
    const int* __restrict__ mask, unsigned short* __restrict__ a_bf,
    unsigned short* __restrict__ w_bf, float* __restrict__ mb,
    int* __restrict__ anym) {
    const int HS_N = M_TOT * HIDDEN / 4;
    const int W_N = HIDDEN * HIDDEN / 4;
    int idx = blockIdx.x * blockDim.x + threadIdx.x;
    if (idx < BB * SS) mb[idx] = mask[idx] ? 0.f : -1e30f;
    if (idx < BB * 32) {
        int b = idx >> 5, t = idx & 31;
        const int* mp = mask + b * SS + t * 64;
        int any = 0;
#pragma unroll 8
        for (int j = 0; j < 64; j++) any |= (mp[j] == 0);
        anym[idx] = any;
    }
    if (idx >= HS_N + 3 * W_N) return;
    if (idx < HS_N) {
        float4 v = ((const float4*)hs)[idx];
        ushort4 o;
        o.x = f2bf(v.x); o.y = f2bf(v.y); o.z = f2bf(v.z); o.w = f2bf(v.w);
        ((ushort4*)a_bf)[idx] = o;
    } else {
        int widx = idx - HS_N;
        const float* src;
        int off;
        if (widx < W_N)        { src = wq; off = widx; }
        else if (widx < 2*W_N) { src = wk; off = widx - W_N; }
        else                   { src = wv; off = widx - 2 * W_N; }
        float4 v = ((const float4*)src)[off];
        ushort4 o;
        o.x = f2bf(v.x); o.y = f2bf(v.y); o.z = f2bf(v.z); o.w = f2bf(v.w);
        ((ushort4*)w_bf)[widx] = o;
    }
}

// ---------------------------------------------------------------------------
// Kernel 2: QKV projection GEMM, m97 structure (verified R6/R8/R12, unchanged).
// ---------------------------------------------------------------------------
__global__ __launch_bounds__(256, 3) void qkv_gemm(
    const unsigned short* __restrict__ A, const unsigned short* __restrict__ W,
    const float* __restrict__ bq, const float* __restrict__ bk,
    const float* __restrict__ bv, unsigned short* __restrict__ qbuf,
    unsigned short* __restrict__ kf, unsigned short* __restrict__ vf) {
    __shared__ unsigned short As[2][128][32];
    __shared__ unsigned short Bs[2][128][32];
    const int tid = threadIdx.x;
    const int m0 = blockIdx.y * 128;
    const int n0 = blockIdx.x * 128;
    const int w = tid >> 6, l = tid & 63;
    const int wm = w >> 1, wn = w & 1;
    const int lrow = l & 15;
    const int g4 = l >> 4;
    const int fcol = (g4 ^ (lrow >> 2)) * 8;

    const int srow = l >> 2;
    const int sslot = (l & 3) ^ ((l >> 4) & 3);
    const unsigned short* pA =
        A + (size_t)(m0 + w * 32 + srow) * HIDDEN + sslot * 8;
    const unsigned short* pB =
        W + (size_t)(n0 + w * 32 + srow) * HIDDEN + sslot * 8;

    f32x4 acc[4][4] = {};

#define STAGE(bb)                                          \
    do {                                                   \
        gl_lds16(pA,               &As[bb][w * 32][0]);    \
        gl_lds16(pA + 16 * HIDDEN, &As[bb][w * 32 + 16][0]); \
        gl_lds16(pB,               &Bs[bb][w * 32][0]);    \
        gl_lds16(pB + 16 * HIDDEN, &Bs[bb][w * 32 + 16][0]); \
        pA += 32; pB += 32;                                \
    } while (0)

    STAGE(0);
    __syncthreads();
    int cur = 0;

    for (int kt = 0; kt < HIDDEN / 32; kt++) {
        if (kt < HIDDEN / 32 - 1) STAGE(cur ^ 1);
        bf16x8 af[4], bfr[4];
#pragma unroll
        for (int mi = 0; mi < 4; mi++)
            af[mi] = *(const bf16x8*)&As[cur][wm * 64 + mi * 16 + lrow][fcol];
#pragma unroll
        for (int ni = 0; ni < 4; ni++)
            bfr[ni] = *(const bf16x8*)&Bs[cur][wn * 64 + ni * 16 + lrow][fcol];
        __builtin_amdgcn_s_setprio(1);
#pragma unroll
        for (int mi = 0; mi < 4; mi++)
#pragma unroll
            for (int ni = 0; ni < 4; ni++)
                acc[mi][ni] = __builtin_amdgcn_mfma_f32_16x16x32_bf16(
                    af[mi], bfr[ni], acc[mi][ni], 0, 0, 0);
        __builtin_amdgcn_s_setprio(0);
        __syncthreads();
        cur ^= 1;
    }
#undef STAGE

    if (n0 < 768) {
#pragma unroll
        for (int mi = 0; mi < 4; mi++)
#pragma unroll
            for (int ni = 0; ni < 4; ni++) {
                int col = n0 + wn * 64 + ni * 16 + lrow;
                float bias = bq[col];
#pragma unroll
                for (int i = 0; i < 4; i++) {
                    int row = m0 + wm * 64 + mi * 16 + g4 * 4 + i;
                    qbuf[(size_t)row * 768 + col] =
                        f2bf((acc[mi][ni][i] + bias) * 0.125f);
                }
            }
    } else if (n0 < 1536) {
#pragma unroll
        for (int mi = 0; mi < 4; mi++)
#pragma unroll
            for (int ni = 0; ni < 4; ni++) {
                int dd = n0 - 768 + wn * 64 + ni * 16 + lrow;
                float bias = bk[dd];
                int hh = dd >> 6, d = dd & 63;
                int gk = d >> 3, d8 = d & 7;
#pragma unroll
                for (int i = 0; i < 4; i++) {
                    int row = m0 + wm * 64 + mi * 16 + g4 * 4 + i;
                    int bb2 = row >> 11, s = row & 2047;
                    int kv16 = s >> 4, ls = s & 15;
                    kf[((size_t)(bb2 * NH + hh) * 128 + kv16) * 1024 +
                       (gk * 16 + ls) * 8 + d8] = f2bf(acc[mi][ni][i] + bias);
                }
            }
    } else {
#pragma unroll
        for (int mi = 0; mi < 4; mi++)
#pragma unroll
            for (int ni = 0; ni < 4; ni++) {
                int dd = n0 - 1536 + wn * 64 + ni * 16 + lrow;
                float bias = bv[dd];
                int hh = dd >> 6, d = dd & 63;
                int dm = d >> 4, lr = d & 15;
                int row0 = m0 + wm * 64 + mi * 16 + g4 * 4;
                int bb2 = row0 >> 11, s = row0 & 2047;
                int kv32 = s >> 5, gv = (s >> 3) & 3, s8 = s & 7;
                ushort4 o;
                o.x = f2bf(acc[mi][ni][0] + bias);
                o.y = f2bf(acc[mi][ni][1] + bias);
                o.z = f2bf(acc[mi][ni][2] + bias);
                o.w = f2bf(acc[mi][ni][3] + bias);
                *(ushort4*)(vf + (((size_t)(bb2 * NH + hh) * 4 + dm) * 64 + kv32) * 512 +
                            (gv * 16 + lr) * 8 + s8) = o;
            }
    }
}

// ---------------------------------------------------------------------------
// Kernel 3: banded flash attention, R12 inner math, with DEPTH-2 prefetch:
// 3 LDS buffers; iter kt issues DMA for kt+2; barriers use counted vmcnt(4)
// so the newest stage stays in flight (drain waits only for DMAs issued a
// full iteration earlier). vmcnt(0) on the last two iterations. Buffer
// written at iter kt was last read at iter kt-1 (reads register-consumed
// before that barrier) -> race-free. All barriers block-uniform.
// ---------------------------------------------------------------------------
__global__ __launch_bounds__(256) void attn_kernel(
    const unsigned short* __restrict__ Qb, const unsigned short* __restrict__ KF,
    const unsigned short* __restrict__ VF, const float* __restrict__ MB,
    const int* __restrict__ ANYM, float* __restrict__ out) {
    __shared__ unsigned short Kl[3][4096];
    __shared__ unsigned short Vl[3][4096];

    const int head_order[12] = {6, 7, 5, 4, 3, 11, 2, 10, 1, 9, 0, 8};
    const int Rtab[12]       = {31, 31, 19, 10, 5, 4, 3, 2, 2, 1, 1, 1};

    const int tid = threadIdx.x;
    const int w = tid >> 6, l = tid & 63;
    // bijective remap (R12, verified): xcd = flat%8 constant per (b,h);
    // slot-major order puts heavy heads first.
    const int flat = blockIdx.y * gridDim.x + blockIdx.x;
    const int xcd = flat & 7;
    const int rem = flat >> 3;        // 0..191
    const int slot = rem >> 5;        // 0..5
    const int qt = rem & 31;
    const int byy = slot * 8 + xcd;   // 0..47
    const int hidx = byy >> 2;
    const int b = byy & 3;
    const int h = head_order[hidx];
    const int R = Rtab[hidx];
    const int bh = b * NH + h;
    const int lrow = l & 15;
    const int g = l >> 4;
    const int q = qt * 64 + w * 16 + lrow;
    const int l8 = l * 8;

    const float slope = (h < 8) ? exp2f(-(float)(h + 1))
                                : exp2f(-((float)(h - 8) + 0.5f));
    const float nslope2 = -slope * LOG2E;
    const float stp = 64.f * nslope2;

    const unsigned short* qp = Qb + (size_t)(b * SS + q) * 768 + h * HD + g * 8;
    const bf16x8 qf0 = *(const bf16x8*)(qp);
    const bf16x8 qf1 = *(const bf16x8*)(qp + 32);

    const unsigned short* kfb = KF + (size_t)bh * 128 * 1024;
    const unsigned short* vfb = VF + (size_t)bh * 4 * 64 * 512;
    const float* mbp = MB + b * SS + g * 4;
    const int* anyp = ANYM + b * 32;

    bf16x8 ones;
#pragma unroll
    for (int j = 0; j < 8; j++) ones[j] = (short)0x3F80;

    f32x4 accT[4] = {};
    f32x4 lacc = {};
    float m_run = 14.0f;   // upper bound on row-max sv; guard stays live
    float ta[16];
    bool need_full = true;

    const int kt_lo = max(0, qt - R);
    const int kt_hi = min(31, qt + R);   // band length >= 2 always (R >= 1)

#define STAGEKV(kt_, bb_)                                                      \
    do {                                                                       \
        const unsigned short* gk_ = kfb + ((size_t)(kt_) * 4 + w) * 1024 + l8; \
        const unsigned short* gv_ =                                            \
            vfb + ((size_t)w * 64 + (size_t)(kt_) * 2) * 512 + l8;             \
        gl_lds16(gk_,       &Kl[bb_][w * 1024]);                               \
        gl_lds16(gk_ + 512, &Kl[bb_][w * 1024 + 512]);                         \
        gl_lds16(gv_,       &Vl[bb_][w * 1024]);                               \
        gl_lds16(gv_ + 512, &Vl[bb_][w * 1024 + 512]);                         \
    } while (0)

    // prologue: stage kt_lo and kt_lo+1; drain only kt_lo's 4 DMAs.
    STAGEKV(kt_lo, 0);
    STAGEKV(kt_lo + 1, 1);
    bar_vm4();

    int cur = 0;
    for (int kt = kt_lo; kt <= kt_hi; kt++) {
        if (kt + 2 <= kt_hi) {
            int db = (cur >= 1) ? cur - 1 : 2;   // (cur+2)%3
            STAGEKV(kt + 2, db);
        }

        f32x4 s4[4];
        __builtin_amdgcn_s_setprio(1);
#pragma unroll
        for (int nf = 0; nf < 4; nf++) {
            bf16x8 k0 = *(const bf16x8*)&Kl[cur][nf * 1024 + l8];
            bf16x8 k1 = *(const bf16x8*)&Kl[cur][nf * 1024 + 512 + l8];
            f32x4 z = {};
            z = __builtin_amdgcn_mfma_f32_16x16x32_bf16(k0, qf0, z, 0, 0, 0);
            z = __builtin_amdgcn_mfma_f32_16x16x32_bf16(k1, qf1, z, 0, 0, 0);
            s4[nf] = z;
        }
        __builtin_amdgcn_s_setprio(0);

        if (need_full || kt == qt || kt == qt + 1) {
            const float fdf = (float)(kt * 64 + g * 4 - q);
#pragma unroll
            for (int nf = 0; nf < 4; nf++)
#pragma unroll
                for (int i = 0; i < 4; i++)
                    ta[nf * 4 + i] = fabsf(fdf + (float)(nf * 16 + i)) * nslope2;
        } else {
            const float d = (kt > qt) ? stp : -stp;
#pragma unroll
            for (int e = 0; e < 16; e++) ta[e] += d;
        }
        need_full = false;

        float sv[16];
#pragma unroll
        for (int nf = 0; nf < 4; nf++)
#pragma unroll
            for (int i = 0; i < 4; i++)
                sv[nf * 4 + i] = fmaf(s4[nf][i], LOG2E, ta[nf * 4 + i]);
        if (anyp[kt]) {
#pragma unroll
            for (int nf = 0; nf < 4; nf++) {
                float4 mbv = *(const float4*)(mbp + kt * 64 + nf * 16);
                sv[nf * 4 + 0] += mbv.x;
                sv[nf * 4 + 1] += mbv.y;
                sv[nf * 4 + 2] += mbv.z;
                sv[nf * 4 + 3] += mbv.w;
            }
        }

        float t0 = fmaxf(fmaxf(sv[0], sv[1]), sv[2]);
        float t1 = fmaxf(fmaxf(sv[3], sv[4]), sv[5]);
        float t2 = fmaxf(fmaxf(sv[6], sv[7]), sv[8]);
        float t3 = fmaxf(fmaxf(sv[9], sv[10]), sv[11]);
        float t4 = fmaxf(fmaxf(sv[12], sv[13]), sv[14]);
        float mt = fmaxf(fmaxf(fmaxf(t0, t1), fmaxf(t2, t3)), fmaxf(t4, sv[15]));
        mt = fmaxf(mt, __shfl_xor(mt, 16));
        mt = fmaxf(mt, __shfl_xor(mt, 32));

        if (!__all(mt <= m_run + 8.0f)) {
            float mnew = fmaxf(m_run, mt);
            float corr = __builtin_amdgcn_exp2f(m_run - mnew);
            m_run = mnew;
#pragma unroll
            for (int i = 0; i < 4; i++) lacc[i] *= corr;
#pragma unroll
            for (int m = 0; m < 4; m++)
#pragma unroll
                for (int i = 0; i < 4; i++) accT[m][i] *= corr;
        }

        float p[16];
#pragma unroll
        for (int e = 0; e < 16; e++)
            p[e] = __builtin_amdgcn_exp2f(sv[e] - m_run);

        unsigned pk[4][2];
#pragma unroll
        for (int nf = 0; nf < 4; nf++) {
            asm("v_cvt_pk_bf16_f32 %0, %1, %2"
                : "=v"(pk[nf][0]) : "v"(p[nf * 4 + 0]), "v"(p[nf * 4 + 1]));
            asm("v_cvt_pk_bf16_f32 %0, %1, %2"
                : "=v"(pk[nf][1]) : "v"(p[nf * 4 + 2]), "v"(p[nf * 4 + 3]));
        }

        const int dstA = ((((g & 1) << 1) | (g >> 1)) << 4) | lrow;
        const int idxA = dstA << 2;
        const int idxB = idxA ^ 128;
        const bool odd = (g & 1);
        unsigned rA0 = __builtin_amdgcn_ds_permute(idxA, (int)(odd ? pk[1][0] : pk[0][0]));
        unsigned rA1 = __builtin_amdgcn_ds_permute(idxA, (int)(odd ? pk[1][1] : pk[0][1]));
        unsigned rB0 = __builtin_amdgcn_ds_permute(idxB, (int)(odd ? pk[0][0] : pk[1][0]));
        unsigned rB1 = __builtin_amdgcn_ds_permute(idxB, (int)(odd ? pk[0][1] : pk[1][1]));
        unsigned rA2 = __builtin_amdgcn_ds_permute(idxA, (int)(odd ? pk[3][0] : pk[2][0]));
        unsigned rA3 = __builtin_amdgcn_ds_permute(idxA, (int)(odd ? pk[3][1] : pk[2][1]));
        unsigned rB2 = __builtin_amdgcn_ds_permute(idxB, (int)(odd ? pk[2][0] : pk[3][0]));
        unsigned rB3 = __builtin_amdgcn_ds_permute(idxB, (int)(odd ? pk[2][1] : pk[3][1]));
        const bool hi = (g >> 1);
        u32x4 uf0, uf1;
        uf0.x = hi ? rB0 : rA0; uf0.y = hi ? rB1 : rA1;
        uf0.z = hi ? rA0 : rB0; uf0.w = hi ? rA1 : rB1;
        uf1.x = hi ? rB2 : rA2; uf1.y = hi ? rB3 : rA3;
        uf1.z = hi ? rA2 : rB2; uf1.w = hi ? rA3 : rB3;
        bf16x8 pf0 = __builtin_bit_cast(bf16x8, uf0);
        bf16x8 pf1 = __builtin_bit_cast(bf16x8, uf1);

        __builtin_amdgcn_s_setprio(1);
#pragma unroll
        for (int m = 0; m < 4; m++) {
            bf16x8 v0 = *(const bf16x8*)&Vl[cur][m * 1024 + l8];
            bf16x8 v1 = *(const bf16x8*)&Vl[cur][m * 1024 + 512 + l8];
            accT[m] = __builtin_amdgcn_mfma_f32_16x16x32_bf16(v0, pf0, accT[m], 0, 0, 0);
            accT[m] = __builtin_amdgcn_mfma_f32_16x16x32_bf16(v1, pf1, accT[m], 0, 0, 0);
        }
        lacc = __builtin_amdgcn_mfma_f32_16x16x32_bf16(ones, pf0, lacc, 0, 0, 0);
        lacc = __builtin_amdgcn_mfma_f32_16x16x32_bf16(ones, pf1, lacc, 0, 0, 0);
        __builtin_amdgcn_s_setprio(0);

        if (kt < kt_hi) {
            if (kt < kt_hi - 1) bar_vm4();
            else bar_vm0();
        }
        cur = (cur == 2) ? 0 : cur + 1;
    }
#undef STAGEKV

    const float inv = 1.0f / lacc[0];
    float* op = out + (size_t)(b * SS + q) * HIDDEN + h * HD + g * 4;
#pragma unroll
    for (int m = 0; m < 4; m++) {
        float4 o;
        o.x = accT[m][0] * inv; o.y = accT[m][1] * inv;
        o.z = accT[m][2] * inv; o.w = accT[m][3] * inv;
        *(float4*)(op + m * 16) = o;
    }
}

// ---------------------------------------------------------------------------
extern "C" void kernel_launch(void* const* d_in, const int* in_sizes, int n_in,
                              void* d_out, int out_size, void* d_ws,
                              size_t ws_size, hipStream_t stream) {
    const float* hs = (const float*)d_in[0];
    const float* wq = (const float*)d_in[1];
    const float* bq = (const float*)d_in[2];
    const float* wk = (const float*)d_in[3];
    const float* bk = (const float*)d_in[4];
    const float* wv = (const float*)d_in[5];
    const float* bv = (const float*)d_in[6];
    const int* mask = (const int*)d_in[7];
    float* out = (float*)d_out;

    unsigned short* a_bf = (unsigned short*)d_ws;
    unsigned short* w_bf = a_bf + (size_t)M_TOT * HIDDEN;
    unsigned short* qbuf = w_bf + (size_t)NQKV * HIDDEN;
    unsigned short* kf = qbuf + (size_t)M_TOT * 768;
    unsigned short* vf = kf + (size_t)BB * NH * 128 * 1024;
    float* mb = (float*)(vf + (size_t)BB * NH * 4 * 64 * 512);
    int* anym = (int*)(mb + BB * SS);

    int castN = (M_TOT * HIDDEN + 3 * HIDDEN * HIDDEN) / 4;
    cast_kernel<<<(castN + 255) / 256, 256, 0, stream>>>(
        hs, wq, wk, wv, mask, a_bf, w_bf, mb, anym);

    dim3 ggrid(NQKV / 128, M_TOT / 128);  // (18, 64)
    qkv_gemm<<<ggrid, 256, 0, stream>>>(a_bf, w_bf, bq, bk, bv, qbuf, kf, vf);

    dim3 agrid(SS / 64, NH * BB);  // (32, 48)
    attn_kernel<<<agrid, 256, 0, stream>>>(qbuf, kf, vf, mb, anym, out);
}